// Round 1
// baseline (2045.378 us; speedup 1.0000x reference)
//
#include <hip/hip_runtime.h>

#define N_NODES 50000
#define N_EDGES 800000

typedef __attribute__((ext_vector_type(8))) short short8;
typedef __attribute__((ext_vector_type(4))) float floatx4;
typedef __attribute__((ext_vector_type(4))) unsigned int u32x4;
typedef unsigned short ushort_t;
typedef unsigned int uint_t;

__device__ __forceinline__ ushort_t f2bf(float f){
  unsigned u = __builtin_bit_cast(unsigned, f);
  u += 0x7fffu + ((u >> 16) & 1u);           // round-to-nearest-even
  return (ushort_t)(u >> 16);
}
__device__ __forceinline__ float bf2f(ushort_t h){
  unsigned u = ((unsigned)h) << 16;
  return __builtin_bit_cast(float, u);
}
__device__ __forceinline__ float sigm(float x){ return 1.f/(1.f+__expf(-x)); }
__device__ __forceinline__ float waveRed(float v){
  #pragma unroll
  for (int o=32;o>0;o>>=1) v += __shfl_xor(v,o);
  return v;
}
// edge_index may be int32 (harness doc) or int64 (reference says jnp.int64).
// mode==1 -> int64 layout: value at dword 2*pos (LE low word, values < 50000).
__device__ __forceinline__ int ldIdx(const int* __restrict__ idx, long long pos, int mode){
  return mode ? idx[pos*2] : idx[pos];
}
__device__ __forceinline__ short8 as_s8(u32x4 v){ return __builtin_bit_cast(short8, v); }

// ---------------- prep kernels ----------------

__global__ void kDetect(const int* __restrict__ idx, int* __restrict__ flag){
  if (threadIdx.x==0 && blockIdx.x==0){
    int any = 0;
    for (int i=1;i<64;i+=2) any |= idx[i];   // all-zero odd dwords => int64
    *flag = (any==0) ? 1 : 0;
  }
}

// LayerNorm(scalar_state) -> bf16 s_norm.  1 wave per node, 4 nodes/block.
__global__ void kLN(const float* __restrict__ s, const float* __restrict__ g,
                    const float* __restrict__ b, ushort_t* __restrict__ out, int N){
  int wid = threadIdx.x >> 6, lane = threadIdx.x & 63;
  int n = blockIdx.x*4 + wid;
  if (n >= N) return;
  float x0 = s[(size_t)n*128 + lane], x1 = s[(size_t)n*128 + 64 + lane];
  float sum = waveRed(x0 + x1);
  float sq  = waveRed(x0*x0 + x1*x1);
  float mean = sum * (1.f/128.f);
  float var  = sq * (1.f/128.f) - mean*mean;
  float rstd = rsqrtf(var + 1e-5f);
  out[(size_t)n*128 + lane]      = f2bf((x0-mean)*rstd*g[lane] + b[lane]);
  out[(size_t)n*128 + 64 + lane] = f2bf((x1-mean)*rstd*g[64+lane] + b[64+lane]);
}

// Reorder W[K][OUT] f32 -> bf16 Wp[kt][q][n][j] (k = kt*32+q*8+j), so that a
// B-fragment (lane: n=lane&15, k=quad*8+j) is one contiguous 16B LDS read.
__global__ void kReorder(const float* __restrict__ W, ushort_t* __restrict__ Wp,
                         int K, int OUT){
  int total = K*OUT;
  for (int o = blockIdx.x*blockDim.x + threadIdx.x; o < total; o += gridDim.x*blockDim.x){
    int j = o & 7; int rest = o >> 3;
    int nn = rest % OUT; int qk = rest / OUT;
    int q = qk & 3, kt = qk >> 2;
    int k = kt*32 + q*8 + j;
    Wp[o] = f2bf(W[(size_t)k*OUT + nn]);
  }
}

// ---------------- counting sort of edges by tgt ----------------

__global__ void kHist(const int* __restrict__ idx, const int* __restrict__ flagp,
                      int* __restrict__ counts){
  int mode = *flagp;
  long long e = (long long)blockIdx.x*256 + threadIdx.x;
  if (e < N_EDGES) atomicAdd(&counts[ldIdx(idx, e, mode)], 1);
}

// single-block exclusive scan (N=50000, 1024 threads, Hillis-Steele chunks)
__global__ void kScan(const int* __restrict__ counts, int* __restrict__ offsets,
                      int* __restrict__ cursor, int n){
  __shared__ int buf[1024];
  __shared__ int carry;
  int tid = threadIdx.x;
  if (tid==0) carry = 0;
  __syncthreads();
  for (int base=0; base<n; base+=1024){
    int i = base + tid;
    int x = (i<n) ? counts[i] : 0;
    buf[tid] = x;
    __syncthreads();
    for (int off=1; off<1024; off<<=1){
      int t_ = 0;
      if (tid >= off) t_ = buf[tid-off];
      __syncthreads();
      buf[tid] += t_;
      __syncthreads();
    }
    int incl = buf[tid];
    int c = carry;
    if (i<n){ offsets[i] = c + incl - x; cursor[i] = c + incl - x; }
    __syncthreads();
    if (tid==1023) carry = c + buf[1023];
    __syncthreads();
  }
}

__global__ void kScatter(const int* __restrict__ idx, const int* __restrict__ flagp,
                         int* __restrict__ cursor, int* __restrict__ sorted){
  int mode = *flagp;
  long long e = (long long)blockIdx.x*256 + threadIdx.x;
  if (e < N_EDGES){
    int t = ldIdx(idx, e, mode);
    int pos = atomicAdd(&cursor[t], 1);
    sorted[pos] = (int)e;
  }
}

// ---------------- fused edge MLP (the big one) ----------------
// Per block: 64 edges. edge_in(64x320 bf16, gathered) @ W1(320x320) -> silu ->
// @ W2(320x320) -> gate -> msg rows [sm_gated(128), sigmoid(vg)(32), ds(32)] bf16.
// LDS A/H buffer stored in MFMA fragment order [kt][mtile][q][m] (16B chunks).
__global__ __launch_bounds__(256,2) void kEdgeMLP(
    const ushort_t* __restrict__ s_norm, const float* __restrict__ edge_attr,
    const ushort_t* __restrict__ W1p, const ushort_t* __restrict__ W2p,
    const float* __restrict__ b1, const float* __restrict__ b2,
    const int* __restrict__ idx, const int* __restrict__ flagp,
    ushort_t* __restrict__ msg)
{
  __shared__ u32x4 sA[2560];          // 40KB: A tile, then H tile, then plain upd
  __shared__ u32x4 sB[1280];          // 20KB: one K-tile (32) of W, frag order
  __shared__ int sTgt[64], sSrc[64];
  const int tid = threadIdx.x;
  const int lane = tid & 63, wid = tid >> 6;
  const int col = lane & 15, quad = lane >> 4;
  const long long e0 = (long long)blockIdx.x * 64;
  const int mode = *flagp;

  if (tid < 64)        sTgt[tid]    = ldIdx(idx, e0 + tid, mode);
  else if (tid < 128)  sSrc[tid-64] = ldIdx(idx, (long long)N_EDGES + e0 + (tid-64), mode);
  __syncthreads();

  // stage A: chunk d -> (kt=d>>8, mtile=(d>>6)&3, q=(d>>4)&3, m=d&15)
  for (int d = tid; d < 2560; d += 256){
    int m = d & 15, q = (d>>4)&3, mtile = (d>>6)&3, kt = d>>8;
    int r = mtile*16 + m, c = kt*4 + q;       // c = 16B chunk along K (8 elems)
    u32x4 v;
    if (c < 16){
      v = *(const u32x4*)(s_norm + (size_t)sTgt[r]*128 + c*8);
    } else if (c < 32){
      v = *(const u32x4*)(s_norm + (size_t)sSrc[r]*128 + (c-16)*8);
    } else {
      const float* fp = edge_attr + (size_t)(e0 + r)*64 + (c-32)*8;
      floatx4 x = *(const floatx4*)fp, y = *(const floatx4*)(fp+4);
      short8 s;
      s[0]=(short)f2bf(x[0]); s[1]=(short)f2bf(x[1]); s[2]=(short)f2bf(x[2]); s[3]=(short)f2bf(x[3]);
      s[4]=(short)f2bf(y[0]); s[5]=(short)f2bf(y[1]); s[6]=(short)f2bf(y[2]); s[7]=(short)f2bf(y[3]);
      v = __builtin_bit_cast(u32x4, s);
    }
    sA[d] = v;
  }

  floatx4 acc[5][4];
  const floatx4 zz = {0.f,0.f,0.f,0.f};
  #pragma unroll
  for (int i=0;i<5;++i)
    #pragma unroll
    for (int j=0;j<4;++j) acc[i][j] = zz;

  const int nb = wid * 80;   // wave's N range (5 tiles of 16)

  // ---- GEMM1 ----
  for (int kt=0; kt<10; ++kt){
    __syncthreads();
    for (int d=tid; d<1280; d+=256)
      sB[d] = *(const u32x4*)(W1p + (size_t)kt*10240 + (size_t)d*8);
    __syncthreads();
    short8 a[4];
    #pragma unroll
    for (int mt=0; mt<4; ++mt)
      a[mt] = as_s8(sA[((kt*4+mt)*4+quad)*16 + col]);
    #pragma unroll
    for (int nt=0; nt<5; ++nt){
      int n = nb + nt*16 + col;
      short8 b = as_s8(sB[quad*320 + n]);
      #pragma unroll
      for (int mt=0; mt<4; ++mt)
        acc[nt][mt] = __builtin_amdgcn_mfma_f32_16x16x32_bf16(a[mt], b, acc[nt][mt], 0,0,0);
    }
  }

  // bias + silu -> H into sA (fragment order), overwriting A
  __syncthreads();
  ushort_t* sH16 = (ushort_t*)sA;
  #pragma unroll
  for (int nt=0; nt<5; ++nt){
    int n = nb + nt*16 + col;
    float bias = b1[n];
    int kt_h = n>>5, q_h = (n>>3)&3, j_h = n&7;
    #pragma unroll
    for (int mt=0; mt<4; ++mt){
      #pragma unroll
      for (int reg=0; reg<4; ++reg){
        int ml = quad*4 + reg;
        float x = acc[nt][mt][reg] + bias;
        float s = x * sigm(x);
        int chunk = ((kt_h*4 + mt)*4 + q_h)*16 + ml;
        sH16[chunk*8 + j_h] = f2bf(s);
      }
    }
  }

  #pragma unroll
  for (int i=0;i<5;++i)
    #pragma unroll
    for (int j=0;j<4;++j) acc[i][j] = zz;

  // ---- GEMM2 ----
  for (int kt=0; kt<10; ++kt){
    __syncthreads();
    for (int d=tid; d<1280; d+=256)
      sB[d] = *(const u32x4*)(W2p + (size_t)kt*10240 + (size_t)d*8);
    __syncthreads();
    short8 a[4];
    #pragma unroll
    for (int mt=0; mt<4; ++mt)
      a[mt] = as_s8(sA[((kt*4+mt)*4+quad)*16 + col]);
    #pragma unroll
    for (int nt=0; nt<5; ++nt){
      int n = nb + nt*16 + col;
      short8 b = as_s8(sB[quad*320 + n]);
      #pragma unroll
      for (int mt=0; mt<4; ++mt)
        acc[nt][mt] = __builtin_amdgcn_mfma_f32_16x16x32_bf16(a[mt], b, acc[nt][mt], 0,0,0);
    }
  }

  // upd + b2 -> sA as plain [64][320] bf16
  __syncthreads();
  #pragma unroll
  for (int nt=0; nt<5; ++nt){
    int n = nb + nt*16 + col;
    float bias = b2[n];
    #pragma unroll
    for (int mt=0; mt<4; ++mt)
      #pragma unroll
      for (int reg=0; reg<4; ++reg){
        int mrow = mt*16 + quad*4 + reg;
        sH16[mrow*320 + n] = f2bf(acc[nt][mt][reg] + bias);
      }
  }
  __syncthreads();

  // gating -> msg rows of 192 bf16 (96 packed uints), coalesced-ish
  for (int pck = tid; pck < 6144; pck += 256){
    int r = pck / 96, u = pck % 96;
    float v0, v1;
    if (u < 64){
      int c0 = u*2;
      float a0 = bf2f(sH16[r*320 + c0]),   g0 = bf2f(sH16[r*320 + 128 + c0]);
      float a1 = bf2f(sH16[r*320 + c0+1]), g1 = bf2f(sH16[r*320 + 128 + c0+1]);
      v0 = a0 * sigm(g0); v1 = a1 * sigm(g1);
    } else if (u < 80){
      int vv = (u-64)*2;
      v0 = sigm(bf2f(sH16[r*320 + 256 + vv]));
      v1 = sigm(bf2f(sH16[r*320 + 256 + vv+1]));
    } else {
      int vv = (u-80)*2;
      v0 = bf2f(sH16[r*320 + 288 + vv]);
      v1 = bf2f(sH16[r*320 + 288 + vv+1]);
    }
    uint_t pk = (uint_t)f2bf(v0) | ((uint_t)f2bf(v1) << 16);
    ((uint_t*)msg)[(size_t)(e0 + r)*96 + u] = pk;
  }
}

// ---------------- per-node aggregation (gather, no float atomics) ----------------
// Writes s1 -> outS, v1 -> outV (residual-added), and bf16 node_in = [LN(s1), vnorm].
__global__ __launch_bounds__(128) void kAgg(
  const ushort_t* __restrict__ msg, const int* __restrict__ sorted,
  const int* __restrict__ counts, const int* __restrict__ offsets,
  const float* __restrict__ scalar_state, const float* __restrict__ vector_state,
  const float* __restrict__ edge_vector, const int* __restrict__ idx,
  const int* __restrict__ flagp,
  const float* __restrict__ pn_g, const float* __restrict__ pn_b,
  float* __restrict__ outS, float* __restrict__ outV, ushort_t* __restrict__ node_in)
{
  int n = blockIdx.x, t = threadIdx.x;
  int mode = *flagp;
  int cnt = counts[n], start = offsets[n];
  int c = t >> 5, vv = t & 31;   // valid for t<96
  float accS = 0.f, accV = 0.f;
  for (int i=0; i<cnt; ++i){
    int e = sorted[start+i];
    const ushort_t* row = msg + (size_t)e*192;
    accS += bf2f(row[t]);
    if (t < 96){
      float sg  = bf2f(row[128+vv]);     // sigmoid(vg), precomputed
      float dsv = bf2f(row[160+vv]);     // ds
      int se = ldIdx(idx, (long long)N_EDGES + e, mode);
      float sv = vector_state[(size_t)se*96 + t];
      float ex = edge_vector[(size_t)e*3], ey = edge_vector[(size_t)e*3+1], ez = edge_vector[(size_t)e*3+2];
      float nr = sqrtf(ex*ex+ey*ey+ez*ez);
      float uc = ((c==0)?ex:(c==1)?ey:ez) / fmaxf(nr, 1e-8f);
      accV += sv*sg + uc*dsv;
    }
  }
  float inv = 1.f / fmaxf((float)cnt, 1.f);
  __shared__ float lv[96];
  __shared__ float pS[2], pQ[2];
  float s1 = scalar_state[(size_t)n*128 + t] + accS*inv;
  outS[(size_t)n*128 + t] = s1;
  if (t < 96){
    float v1 = vector_state[(size_t)n*96 + t] + accV*inv;
    outV[(size_t)n*96 + t] = v1;
    lv[t] = v1;
  }
  float wsum = waveRed(s1), wsq = waveRed(s1*s1);
  if ((t&63)==0){ pS[t>>6]=wsum; pQ[t>>6]=wsq; }
  __syncthreads();
  float mean = (pS[0]+pS[1]) * (1.f/128.f);
  float var  = (pQ[0]+pQ[1]) * (1.f/128.f) - mean*mean;
  float rstd = rsqrtf(var + 1e-5f);
  node_in[(size_t)n*160 + t] = f2bf((s1-mean)*rstd*pn_g[t] + pn_b[t]);
  if (t < 32){
    float a = lv[t], b = lv[32+t], d = lv[64+t];
    float vn = sqrtf(fmaxf(a*a+b*b+d*d, 1e-8f));
    node_in[(size_t)n*160 + 128 + t] = f2bf(vn);
  }
}

// ---------------- fused node MLP (M=32 tile, in-place update of d_out) ----------------
__global__ __launch_bounds__(256,2) void kNodeMLP(
  const ushort_t* __restrict__ node_in, const ushort_t* __restrict__ W1np,
  const ushort_t* __restrict__ W2np, const float* __restrict__ b1,
  const float* __restrict__ b2, float* __restrict__ outS, float* __restrict__ outV)
{
  __shared__ u32x4 sA[640];    // 10KB node_in tile, frag order [kt5][mt2][q4][m16]
  __shared__ u32x4 sH[1152];   // 18KB h2 tile, frag order [kt9][mt2][q4][m16]
  __shared__ u32x4 sB[1152];   // 18KB W k-tile
  const int tid = threadIdx.x;
  const int lane = tid & 63, wid = tid >> 6;
  const int col = lane & 15, quad = lane >> 4;
  const int wm = wid & 1, wn = wid >> 1;
  const int rbase = blockIdx.x * 32;

  for (int d = tid; d < 640; d += 256){
    int m = d & 15, q = (d>>4)&3, mtile = (d>>6)&1, kt = d>>7;
    int r = rbase + mtile*16 + m, cc = kt*4 + q;
    u32x4 v = {0,0,0,0};
    if (r < N_NODES) v = *(const u32x4*)(node_in + (size_t)r*160 + cc*8);
    sA[d] = v;
  }

  const floatx4 zz = {0.f,0.f,0.f,0.f};
  floatx4 acc[9];
  #pragma unroll
  for (int i=0;i<9;++i) acc[i] = zz;

  // GEMM1: K=160, N=288; wave: mtile=wm, 9 ntiles at wn*144
  for (int kt=0; kt<5; ++kt){
    __syncthreads();
    for (int d=tid; d<1152; d+=256)
      sB[d] = *(const u32x4*)(W1np + (size_t)kt*9216 + (size_t)d*8);
    __syncthreads();
    short8 a = as_s8(sA[((kt*2+wm)*4+quad)*16 + col]);
    #pragma unroll
    for (int jt=0; jt<9; ++jt){
      int n = wn*144 + jt*16 + col;
      short8 b = as_s8(sB[quad*288 + n]);
      acc[jt] = __builtin_amdgcn_mfma_f32_16x16x32_bf16(a, b, acc[jt], 0,0,0);
    }
  }
  __syncthreads();
  ushort_t* sH16 = (ushort_t*)sH;
  #pragma unroll
  for (int jt=0; jt<9; ++jt){
    int n = wn*144 + jt*16 + col;
    float bias = b1[n];
    int kt_h = n>>5, q_h = (n>>3)&3, j_h = n&7;
    #pragma unroll
    for (int reg=0; reg<4; ++reg){
      int ml = quad*4 + reg;
      float x = acc[jt][reg] + bias;
      float s = x * sigm(x);
      int chunk = ((kt_h*2 + wm)*4 + q_h)*16 + ml;
      sH16[chunk*8 + j_h] = f2bf(s);
    }
  }

  floatx4 acc2[5];
  #pragma unroll
  for (int i=0;i<5;++i) acc2[i] = zz;

  // GEMM2: K=288, N=160; 5 ntiles at wn*80
  for (int kt=0; kt<9; ++kt){
    __syncthreads();
    for (int d=tid; d<640; d+=256)
      sB[d] = *(const u32x4*)(W2np + (size_t)kt*5120 + (size_t)d*8);
    __syncthreads();
    short8 a = as_s8(sH[((kt*2+wm)*4+quad)*16 + col]);
    #pragma unroll
    for (int jt=0; jt<5; ++jt){
      int n = wn*80 + jt*16 + col;
      short8 b = as_s8(sB[quad*160 + n]);
      acc2[jt] = __builtin_amdgcn_mfma_f32_16x16x32_bf16(a, b, acc2[jt], 0,0,0);
    }
  }

  #pragma unroll
  for (int jt=0; jt<5; ++jt){
    int n = wn*80 + jt*16 + col;
    float bias = b2[n];
    #pragma unroll
    for (int reg=0; reg<4; ++reg){
      int ml = quad*4 + reg;
      int r = rbase + wm*16 + ml;
      if (r < N_NODES){
        float val = acc2[jt][reg] + bias;
        if (n < 128){
          float* o = outS + (size_t)r*128 + n;
          *o = *o + val;                       // scalar_state += scalar_delta
        } else {
          int vv = n - 128;
          float f = 1.f + 0.1f * tanhf(val);   // vector gate, broadcast over 3 comps
          float* o = outV + (size_t)r*96 + vv;
          o[0] *= f; o[32] *= f; o[64] *= f;
        }
      }
    }
  }
}

// ---------------- launch ----------------

extern "C" void kernel_launch(void* const* d_in, const int* in_sizes, int n_in,
                              void* d_out, int out_size, void* d_ws, size_t ws_size,
                              hipStream_t stream)
{
  const float* scalar_state = (const float*)d_in[0];
  const float* vector_state = (const float*)d_in[1];
  const float* edge_attr    = (const float*)d_in[2];
  const float* edge_vector  = (const float*)d_in[3];
  const float* sn_g = (const float*)d_in[4];
  const float* sn_b = (const float*)d_in[5];
  const float* pn_g = (const float*)d_in[6];
  const float* pn_b = (const float*)d_in[7];
  const float* e_w1 = (const float*)d_in[8];
  const float* e_b1 = (const float*)d_in[9];
  const float* e_w2 = (const float*)d_in[10];
  const float* e_b2 = (const float*)d_in[11];
  const float* n_w1 = (const float*)d_in[12];
  const float* n_b1 = (const float*)d_in[13];
  const float* n_w2 = (const float*)d_in[14];
  const float* n_b2 = (const float*)d_in[15];
  const int*   eidx = (const int*)d_in[16];

  char* p = (char*)d_ws;
  auto take = [&](size_t bytes)->char*{
    char* r = p; p += (bytes + 255) & ~(size_t)255; return r;
  };
  int*      flag    = (int*)take(4);
  ushort_t* s_norm  = (ushort_t*)take((size_t)N_NODES*128*2);
  ushort_t* W1p     = (ushort_t*)take((size_t)320*320*2);
  ushort_t* W2p     = (ushort_t*)take((size_t)320*320*2);
  ushort_t* W1np    = (ushort_t*)take((size_t)160*288*2);
  ushort_t* W2np    = (ushort_t*)take((size_t)288*160*2);
  int*      counts  = (int*)take((size_t)N_NODES*4);
  int*      offsets = (int*)take((size_t)N_NODES*4);
  int*      cursor  = (int*)take((size_t)N_NODES*4);
  int*      sorted  = (int*)take((size_t)N_EDGES*4);
  ushort_t* msg     = (ushort_t*)take((size_t)N_EDGES*192*2);
  ushort_t* node_in = (ushort_t*)take((size_t)N_NODES*160*2);
  (void)ws_size; (void)in_sizes; (void)n_in; (void)out_size;

  float* outS = (float*)d_out;
  float* outV = outS + (size_t)N_NODES*128;

  kDetect<<<1, 64, 0, stream>>>(eidx, flag);
  kLN<<<(N_NODES+3)/4, 256, 0, stream>>>(scalar_state, sn_g, sn_b, s_norm, N_NODES);
  kReorder<<<160, 256, 0, stream>>>(e_w1, W1p, 320, 320);
  kReorder<<<160, 256, 0, stream>>>(e_w2, W2p, 320, 320);
  kReorder<<<160, 256, 0, stream>>>(n_w1, W1np, 160, 288);
  kReorder<<<160, 256, 0, stream>>>(n_w2, W2np, 288, 160);
  hipMemsetAsync(counts, 0, (size_t)N_NODES*4, stream);
  kHist<<<N_EDGES/256, 256, 0, stream>>>(eidx, flag, counts);
  kScan<<<1, 1024, 0, stream>>>(counts, offsets, cursor, N_NODES);
  kScatter<<<N_EDGES/256, 256, 0, stream>>>(eidx, flag, cursor, sorted);
  kEdgeMLP<<<N_EDGES/64, 256, 0, stream>>>(s_norm, edge_attr, W1p, W2p,
                                           e_b1, e_b2, eidx, flag, msg);
  kAgg<<<N_NODES, 128, 0, stream>>>(msg, sorted, counts, offsets,
                                    scalar_state, vector_state, edge_vector,
                                    eidx, flag, pn_g, pn_b, outS, outV, node_in);
  kNodeMLP<<<(N_NODES+31)/32, 256, 0, stream>>>(node_in, W1np, W2np, n_b1, n_b2, outS, outV);
}

// Round 2
// 1576.348 us; speedup vs baseline: 1.2975x; 1.2975x over previous
//
#include <hip/hip_runtime.h>

#define N_NODES 50000
#define N_EDGES 800000

typedef __attribute__((ext_vector_type(8))) short short8;
typedef __attribute__((ext_vector_type(4))) float floatx4;
typedef __attribute__((ext_vector_type(4))) unsigned int u32x4;
typedef unsigned short ushort_t;
typedef unsigned int uint_t;

__device__ __forceinline__ ushort_t f2bf(float f){
  unsigned u = __builtin_bit_cast(unsigned, f);
  u += 0x7fffu + ((u >> 16) & 1u);           // round-to-nearest-even
  return (ushort_t)(u >> 16);
}
__device__ __forceinline__ float bf2f(ushort_t h){
  unsigned u = ((unsigned)h) << 16;
  return __builtin_bit_cast(float, u);
}
__device__ __forceinline__ float sigm(float x){ return 1.f/(1.f+__expf(-x)); }
__device__ __forceinline__ float waveRed(float v){
  #pragma unroll
  for (int o=32;o>0;o>>=1) v += __shfl_xor(v,o);
  return v;
}
__device__ __forceinline__ int ldIdx(const int* __restrict__ idx, long long pos, int mode){
  return mode ? idx[pos*2] : idx[pos];
}
__device__ __forceinline__ short8 as_s8(u32x4 v){ return __builtin_bit_cast(short8, v); }

// async global->LDS 16B: lds dest = wave-uniform base + lane*16
__device__ __forceinline__ void gl_lds16(const ushort_t* g, ushort_t* l){
  __builtin_amdgcn_global_load_lds(
    (const __attribute__((address_space(1))) unsigned int*)(unsigned long long)(uintptr_t)g,
    (__attribute__((address_space(3))) unsigned int*)(unsigned int)(uintptr_t)l,
    16, 0, 0);
}

__device__ __forceinline__ u32x4 bfadd8(u32x4 a, u32x4 b){
  u32x4 r;
  #pragma unroll
  for (int i=0;i<4;++i){
    float alo = __builtin_bit_cast(float, a[i]<<16);
    float ahi = __builtin_bit_cast(float, a[i]&0xffff0000u);
    float blo = __builtin_bit_cast(float, b[i]<<16);
    float bhi = __builtin_bit_cast(float, b[i]&0xffff0000u);
    unsigned lo = f2bf(alo+blo);
    unsigned hi = f2bf(ahi+bhi);
    r[i] = lo | (hi<<16);
  }
  return r;
}
__device__ __forceinline__ short8 pack8(floatx4 x, floatx4 y){
  short8 s;
  s[0]=(short)f2bf(x[0]); s[1]=(short)f2bf(x[1]); s[2]=(short)f2bf(x[2]); s[3]=(short)f2bf(x[3]);
  s[4]=(short)f2bf(y[0]); s[5]=(short)f2bf(y[1]); s[6]=(short)f2bf(y[2]); s[7]=(short)f2bf(y[3]);
  return s;
}

// ---------------- prep kernels ----------------

__global__ void kDetect(const int* __restrict__ idx, int* __restrict__ flag){
  if (threadIdx.x==0 && blockIdx.x==0){
    int any = 0;
    for (int i=1;i<64;i+=2) any |= idx[i];   // all-zero odd dwords => int64
    *flag = (any==0) ? 1 : 0;
  }
}

__global__ void kLN(const float* __restrict__ s, const float* __restrict__ g,
                    const float* __restrict__ b, ushort_t* __restrict__ out, int N){
  int wid = threadIdx.x >> 6, lane = threadIdx.x & 63;
  int n = blockIdx.x*4 + wid;
  if (n >= N) return;
  float x0 = s[(size_t)n*128 + lane], x1 = s[(size_t)n*128 + 64 + lane];
  float sum = waveRed(x0 + x1);
  float sq  = waveRed(x0*x0 + x1*x1);
  float mean = sum * (1.f/128.f);
  float var  = sq * (1.f/128.f) - mean*mean;
  float rstd = rsqrtf(var + 1e-5f);
  out[(size_t)n*128 + lane]      = f2bf((x0-mean)*rstd*g[lane] + b[lane]);
  out[(size_t)n*128 + 64 + lane] = f2bf((x1-mean)*rstd*g[64+lane] + b[64+lane]);
}

// W[K][OUT] f32 -> bf16 Wp[kt][q][n][j] (k = kt*32+q*8+j): B-frag = contiguous 16B
__global__ void kReorder(const float* __restrict__ W, ushort_t* __restrict__ Wp,
                         int K, int OUT){
  int total = K*OUT;
  for (int o = blockIdx.x*blockDim.x + threadIdx.x; o < total; o += gridDim.x*blockDim.x){
    int j = o & 7; int rest = o >> 3;
    int nn = rest % OUT; int qk = rest / OUT;
    int q = qk & 3, kt = qk >> 2;
    int k = kt*32 + q*8 + j;
    Wp[o] = f2bf(W[(size_t)k*OUT + nn]);
  }
}

// Wab[k<128][n<640]: n<320 -> e_w1[k][n] (tgt path), n>=320 -> e_w1[128+k][n-320] (src path)
__global__ void kReorderAB(const float* __restrict__ W, ushort_t* __restrict__ Wp){
  int total = 128*640;
  for (int o = blockIdx.x*blockDim.x + threadIdx.x; o < total; o += gridDim.x*blockDim.x){
    int j = o & 7; int rest = o >> 3;
    int nn = rest % 640; int qk = rest / 640;
    int q = qk & 3, kt = qk >> 2;
    int k = kt*32 + q*8 + j;
    float v = (nn < 320) ? W[(size_t)k*320 + nn] : W[(size_t)(128+k)*320 + (nn-320)];
    Wp[o] = f2bf(v);
  }
}

// ---------------- counting sort of edges by tgt ----------------

__global__ void kHist(const int* __restrict__ idx, const int* __restrict__ flagp,
                      int* __restrict__ counts){
  int mode = *flagp;
  long long e = (long long)blockIdx.x*256 + threadIdx.x;
  if (e < N_EDGES) atomicAdd(&counts[ldIdx(idx, e, mode)], 1);
}

__global__ void kScan(const int* __restrict__ counts, int* __restrict__ offsets,
                      int* __restrict__ cursor, int n){
  __shared__ int buf[1024];
  __shared__ int carry;
  int tid = threadIdx.x;
  if (tid==0) carry = 0;
  __syncthreads();
  for (int base=0; base<n; base+=1024){
    int i = base + tid;
    int x = (i<n) ? counts[i] : 0;
    buf[tid] = x;
    __syncthreads();
    for (int off=1; off<1024; off<<=1){
      int t_ = 0;
      if (tid >= off) t_ = buf[tid-off];
      __syncthreads();
      buf[tid] += t_;
      __syncthreads();
    }
    int incl = buf[tid];
    int c = carry;
    if (i<n){ offsets[i] = c + incl - x; cursor[i] = c + incl - x; }
    __syncthreads();
    if (tid==1023) carry = c + buf[1023];
    __syncthreads();
  }
}

__global__ void kScatter(const int* __restrict__ idx, const int* __restrict__ flagp,
                         int* __restrict__ cursor, int* __restrict__ sorted){
  int mode = *flagp;
  long long e = (long long)blockIdx.x*256 + threadIdx.x;
  if (e < N_EDGES){
    int t = ldIdx(idx, e, mode);
    int pos = atomicAdd(&cursor[t], 1);
    sorted[pos] = (int)e;
  }
}

// ---------------- node-level P precompute: P[n][0:320]=s_norm@W1a+b1, [320:640]=s_norm@W1b ----
__global__ __launch_bounds__(256,2) void kNodeP(
  const ushort_t* __restrict__ s_norm, const ushort_t* __restrict__ Wabp,
  const float* __restrict__ b1, ushort_t* __restrict__ P)
{
  __shared__ u32x4 sA[1024];   // 16KB: 64 nodes x 128 K, frag order
  __shared__ u32x4 sB[2560];   // 40KB: one K=32 tile of Wab (32x640)
  const int tid = threadIdx.x;
  const int lane = tid & 63, wid = tid >> 6;
  const int col = lane & 15, quad = lane >> 4;
  const int nb0 = blockIdx.x * 64;

  for (int i=0;i<4;++i){
    int d = i*256 + tid;
    int m=d&15, q=(d>>4)&3, mt=(d>>6)&3, kt=d>>8;
    int node = nb0 + mt*16 + m;
    u32x4 v = {0,0,0,0};
    if (node < N_NODES) v = *(const u32x4*)(s_norm + (size_t)node*128 + (kt*4+q)*8);
    sA[d] = v;
  }

  const floatx4 zz = {0.f,0.f,0.f,0.f};
  floatx4 acc[10][4];
  #pragma unroll
  for (int i=0;i<10;++i)
    #pragma unroll
    for (int j=0;j<4;++j) acc[i][j] = zz;

  for (int kt=0; kt<4; ++kt){
    for (int i=0;i<10;++i){
      int cb = i*256 + wid*64;
      gl_lds16(Wabp + ((size_t)kt*2560 + cb + lane)*8, (ushort_t*)&sB[cb]);
    }
    __syncthreads();
    short8 a[4];
    #pragma unroll
    for (int mt=0; mt<4; ++mt)
      a[mt] = as_s8(sA[((kt*4+mt)*4+quad)*16 + col]);
    #pragma unroll
    for (int nt=0; nt<10; ++nt){
      int n = wid*160 + nt*16 + col;
      short8 b = as_s8(sB[quad*640 + n]);
      #pragma unroll
      for (int mt=0; mt<4; ++mt)
        acc[nt][mt] = __builtin_amdgcn_mfma_f32_16x16x32_bf16(a[mt], b, acc[nt][mt], 0,0,0);
    }
    __syncthreads();
  }

  #pragma unroll
  for (int nt=0; nt<10; ++nt){
    int n = wid*160 + nt*16 + col;
    float bias = (n < 320) ? b1[n] : 0.f;
    #pragma unroll
    for (int mt=0; mt<4; ++mt)
      #pragma unroll
      for (int reg=0; reg<4; ++reg){
        int node = nb0 + mt*16 + quad*4 + reg;
        if (node < N_NODES)
          P[(size_t)node*640 + n] = f2bf(acc[nt][mt][reg] + bias);
      }
  }
}

// ---------------- fused edge MLP v2 ----------------
// Per block 64 edges. h = silu(P[tgt](+b1) + P[src,320:] + edge_attr@W1c); upd = h@W2+b2;
// gate -> msg [sm*sig(sg) 128 | sig(vg) 32 | ds 32] bf16.
__global__ __launch_bounds__(256,2) void kEdgeMLP(
    const ushort_t* __restrict__ P, const float* __restrict__ edge_attr,
    const ushort_t* __restrict__ W1cp, const ushort_t* __restrict__ W2p,
    const float* __restrict__ b2, const int* __restrict__ idx,
    const int* __restrict__ flagp, ushort_t* __restrict__ msg)
{
  __shared__ u32x4 sA[2560];   // 40KB: P-sum -> h (frag order) -> plain upd
  __shared__ u32x4 sB[2560];   // 40KB: one K=64 weight tile
  const int tid = threadIdx.x;
  const int lane = tid & 63, wid = tid >> 6;
  const int col = lane & 15, quad = lane >> 4;
  const long long e0 = (long long)blockIdx.x * 64;
  const int mode = *flagp;
  const int nb = wid * 80;

  // issue W1c (64x320 = 40KB) async into sB
  for (int i=0;i<10;++i){
    int cb = i*256 + wid*64;
    gl_lds16(W1cp + (size_t)(cb + lane)*8, (ushort_t*)&sB[cb]);
  }

  // edge_attr A-fragments straight to registers (fp32 -> bf16)
  short8 aQ[2][4];
  #pragma unroll
  for (int kq=0; kq<2; ++kq)
    #pragma unroll
    for (int mt=0; mt<4; ++mt){
      const float* fp = edge_attr + (size_t)(e0 + mt*16 + col)*64 + kq*32 + quad*8;
      aQ[kq][mt] = pack8(*(const floatx4*)fp, *(const floatx4*)(fp+4));
    }

  // stage sP = P[tgt][n] + P[src][320+n] into sA (A-frag order over k=n)
  for (int i=0;i<10;++i){
    int d = i*256 + tid;
    int m=d&15, q=(d>>4)&3, mt=(d>>6)&3, kt=d>>8;
    int r = mt*16 + m;
    int tg = ldIdx(idx, e0 + r, mode);
    int sr = ldIdx(idx, (long long)N_EDGES + e0 + r, mode);
    int n0 = kt*32 + q*8;
    u32x4 a = *(const u32x4*)(P + (size_t)tg*640 + n0);
    u32x4 b = *(const u32x4*)(P + (size_t)sr*640 + 320 + n0);
    sA[d] = bfadd8(a, b);
  }
  __syncthreads();

  const floatx4 zz = {0.f,0.f,0.f,0.f};
  floatx4 acc[5][4];
  #pragma unroll
  for (int i=0;i<5;++i)
    #pragma unroll
    for (int j=0;j<4;++j) acc[i][j] = zz;

  // Q GEMM: edge_attr @ W1c (K=64)
  #pragma unroll
  for (int kq=0; kq<2; ++kq)
    #pragma unroll
    for (int nt=0; nt<5; ++nt){
      short8 b = as_s8(sB[(kq*4+quad)*320 + nb + nt*16 + col]);
      #pragma unroll
      for (int mt=0; mt<4; ++mt)
        acc[nt][mt] = __builtin_amdgcn_mfma_f32_16x16x32_bf16(aQ[kq][mt], b, acc[nt][mt], 0,0,0);
    }

  // epi1: h = silu(acc + sP) in place (per-element owner bijection: no hazard)
  ushort_t* sH16 = (ushort_t*)sA;
  #pragma unroll
  for (int nt=0; nt<5; ++nt){
    int n = nb + nt*16 + col;
    int kt_h = n>>5, q_h = (n>>3)&3, j_h = n&7;
    #pragma unroll
    for (int mt=0; mt<4; ++mt)
      #pragma unroll
      for (int reg=0; reg<4; ++reg){
        int ml = quad*4 + reg;
        int a2 = (((kt_h*4 + mt)*4 + q_h)*16 + ml)*8 + j_h;
        float x = acc[nt][mt][reg] + bf2f(sH16[a2]);
        sH16[a2] = f2bf(x * sigm(x));
      }
  }
  #pragma unroll
  for (int i=0;i<5;++i)
    #pragma unroll
    for (int j=0;j<4;++j) acc[i][j] = zz;
  __syncthreads();

  // GEMM2: 5 rounds of K=64 W2 tiles
  for (int kt=0; kt<5; ++kt){
    for (int i=0;i<10;++i){
      int cb = i*256 + wid*64;
      gl_lds16(W2p + ((size_t)kt*2560 + cb + lane)*8, (ushort_t*)&sB[cb]);
    }
    short8 a[2][4];
    #pragma unroll
    for (int kh=0; kh<2; ++kh)
      #pragma unroll
      for (int mt=0; mt<4; ++mt)
        a[kh][mt] = as_s8(sA[(((kt*2+kh)*4+mt)*4+quad)*16 + col]);
    __syncthreads();
    #pragma unroll
    for (int kh=0; kh<2; ++kh)
      #pragma unroll
      for (int nt=0; nt<5; ++nt){
        short8 b = as_s8(sB[(kh*4+quad)*320 + nb + nt*16 + col]);
        #pragma unroll
        for (int mt=0; mt<4; ++mt)
          acc[nt][mt] = __builtin_amdgcn_mfma_f32_16x16x32_bf16(a[kh][mt], b, acc[nt][mt], 0,0,0);
      }
    __syncthreads();
  }

  // epi2: upd + b2 -> plain [64][320] bf16 in sA
  #pragma unroll
  for (int nt=0; nt<5; ++nt){
    int n = nb + nt*16 + col;
    float bias = b2[n];
    #pragma unroll
    for (int mt=0; mt<4; ++mt)
      #pragma unroll
      for (int reg=0; reg<4; ++reg){
        int mrow = mt*16 + quad*4 + reg;
        sH16[mrow*320 + n] = f2bf(acc[nt][mt][reg] + bias);
      }
  }
  __syncthreads();

  // gating -> msg rows of 192 bf16 (96 packed uints)
  for (int pck = tid; pck < 6144; pck += 256){
    int r = pck / 96, u = pck % 96;
    float v0, v1;
    if (u < 64){
      int c0 = u*2;
      float a0 = bf2f(sH16[r*320 + c0]),   g0 = bf2f(sH16[r*320 + 128 + c0]);
      float a1 = bf2f(sH16[r*320 + c0+1]), g1 = bf2f(sH16[r*320 + 128 + c0+1]);
      v0 = a0 * sigm(g0); v1 = a1 * sigm(g1);
    } else if (u < 80){
      int vv = (u-64)*2;
      v0 = sigm(bf2f(sH16[r*320 + 256 + vv]));
      v1 = sigm(bf2f(sH16[r*320 + 256 + vv+1]));
    } else {
      int vv = (u-80)*2;
      v0 = bf2f(sH16[r*320 + 288 + vv]);
      v1 = bf2f(sH16[r*320 + 288 + vv+1]);
    }
    uint_t pk = (uint_t)f2bf(v0) | ((uint_t)f2bf(v1) << 16);
    ((uint_t*)msg)[(size_t)(e0 + r)*96 + u] = pk;
  }
}

// ---------------- per-node aggregation ----------------
__global__ __launch_bounds__(128) void kAgg(
  const ushort_t* __restrict__ msg, const int* __restrict__ sorted,
  const int* __restrict__ counts, const int* __restrict__ offsets,
  const float* __restrict__ scalar_state, const float* __restrict__ vector_state,
  const float* __restrict__ edge_vector, const int* __restrict__ idx,
  const int* __restrict__ flagp,
  const float* __restrict__ pn_g, const float* __restrict__ pn_b,
  float* __restrict__ outS, float* __restrict__ outV, ushort_t* __restrict__ node_in)
{
  int n = blockIdx.x, t = threadIdx.x;
  int mode = *flagp;
  int cnt = counts[n], start = offsets[n];
  int c = t >> 5, vv = t & 31;
  float accS = 0.f, accV = 0.f;
  for (int i=0; i<cnt; ++i){
    int e = sorted[start+i];
    const ushort_t* row = msg + (size_t)e*192;
    accS += bf2f(row[t]);
    if (t < 96){
      float sg  = bf2f(row[128+vv]);
      float dsv = bf2f(row[160+vv]);
      int se = ldIdx(idx, (long long)N_EDGES + e, mode);
      float sv = vector_state[(size_t)se*96 + t];
      float ex = edge_vector[(size_t)e*3], ey = edge_vector[(size_t)e*3+1], ez = edge_vector[(size_t)e*3+2];
      float nr = sqrtf(ex*ex+ey*ey+ez*ez);
      float uc = ((c==0)?ex:(c==1)?ey:ez) / fmaxf(nr, 1e-8f);
      accV += sv*sg + uc*dsv;
    }
  }
  float inv = 1.f / fmaxf((float)cnt, 1.f);
  __shared__ float lv[96];
  __shared__ float pS[2], pQ[2];
  float s1 = scalar_state[(size_t)n*128 + t] + accS*inv;
  outS[(size_t)n*128 + t] = s1;
  if (t < 96){
    float v1 = vector_state[(size_t)n*96 + t] + accV*inv;
    outV[(size_t)n*96 + t] = v1;
    lv[t] = v1;
  }
  float wsum = waveRed(s1), wsq = waveRed(s1*s1);
  if ((t&63)==0){ pS[t>>6]=wsum; pQ[t>>6]=wsq; }
  __syncthreads();
  float mean = (pS[0]+pS[1]) * (1.f/128.f);
  float var  = (pQ[0]+pQ[1]) * (1.f/128.f) - mean*mean;
  float rstd = rsqrtf(var + 1e-5f);
  node_in[(size_t)n*160 + t] = f2bf((s1-mean)*rstd*pn_g[t] + pn_b[t]);
  if (t < 32){
    float a = lv[t], b = lv[32+t], d = lv[64+t];
    float vn = sqrtf(fmaxf(a*a+b*b+d*d, 1e-8f));
    node_in[(size_t)n*160 + 128 + t] = f2bf(vn);
  }
}

// ---------------- fused node MLP ----------------
__global__ __launch_bounds__(256,2) void kNodeMLP(
  const ushort_t* __restrict__ node_in, const ushort_t* __restrict__ W1np,
  const ushort_t* __restrict__ W2np, const float* __restrict__ b1,
  const float* __restrict__ b2, float* __restrict__ outS, float* __restrict__ outV)
{
  __shared__ u32x4 sA[640];
  __shared__ u32x4 sH[1152];
  __shared__ u32x4 sB[1152];
  const int tid = threadIdx.x;
  const int lane = tid & 63, wid = tid >> 6;
  const int col = lane & 15, quad = lane >> 4;
  const int wm = wid & 1, wn = wid >> 1;
  const int rbase = blockIdx.x * 32;

  for (int d = tid; d < 640; d += 256){
    int m = d & 15, q = (d>>4)&3, mtile = (d>>6)&1, kt = d>>7;
    int r = rbase + mtile*16 + m, cc = kt*4 + q;
    u32x4 v = {0,0,0,0};
    if (r < N_NODES) v = *(const u32x4*)(node_in + (size_t)r*160 + cc*8);
    sA[d] = v;
  }

  const floatx4 zz = {0.f,0.f,0.f,0.f};
  floatx4 acc[9];
  #pragma unroll
  for (int i=0;i<9;++i) acc[i] = zz;

  for (int kt=0; kt<5; ++kt){
    __syncthreads();
    for (int d=tid; d<1152; d+=256)
      sB[d] = *(const u32x4*)(W1np + (size_t)kt*9216 + (size_t)d*8);
    __syncthreads();
    short8 a = as_s8(sA[((kt*2+wm)*4+quad)*16 + col]);
    #pragma unroll
    for (int jt=0; jt<9; ++jt){
      int n = wn*144 + jt*16 + col;
      short8 b = as_s8(sB[quad*288 + n]);
      acc[jt] = __builtin_amdgcn_mfma_f32_16x16x32_bf16(a, b, acc[jt], 0,0,0);
    }
  }
  __syncthreads();
  ushort_t* sH16 = (ushort_t*)sH;
  #pragma unroll
  for (int jt=0; jt<9; ++jt){
    int n = wn*144 + jt*16 + col;
    float bias = b1[n];
    int kt_h = n>>5, q_h = (n>>3)&3, j_h = n&7;
    #pragma unroll
    for (int reg=0; reg<4; ++reg){
      int ml = quad*4 + reg;
      float x = acc[jt][reg] + bias;
      float s = x * sigm(x);
      int chunk = ((kt_h*2 + wm)*4 + q_h)*16 + ml;
      sH16[chunk*8 + j_h] = f2bf(s);
    }
  }

  floatx4 acc2[5];
  #pragma unroll
  for (int i=0;i<5;++i) acc2[i] = zz;

  for (int kt=0; kt<9; ++kt){
    __syncthreads();
    for (int d=tid; d<640; d+=256)
      sB[d] = *(const u32x4*)(W2np + (size_t)kt*5120 + (size_t)d*8);
    __syncthreads();
    short8 a = as_s8(sH[((kt*2+wm)*4+quad)*16 + col]);
    #pragma unroll
    for (int jt=0; jt<5; ++jt){
      int n = wn*80 + jt*16 + col;
      short8 b = as_s8(sB[quad*160 + n]);
      acc2[jt] = __builtin_amdgcn_mfma_f32_16x16x32_bf16(a, b, acc2[jt], 0,0,0);
    }
  }

  #pragma unroll
  for (int jt=0; jt<5; ++jt){
    int n = wn*80 + jt*16 + col;
    float bias = b2[n];
    #pragma unroll
    for (int reg=0; reg<4; ++reg){
      int ml = quad*4 + reg;
      int r = rbase + wm*16 + ml;
      if (r < N_NODES){
        float val = acc2[jt][reg] + bias;
        if (n < 128){
          float* o = outS + (size_t)r*128 + n;
          *o = *o + val;
        } else {
          int vv = n - 128;
          float f = 1.f + 0.1f * tanhf(val);
          float* o = outV + (size_t)r*96 + vv;
          o[0] *= f; o[32] *= f; o[64] *= f;
        }
      }
    }
  }
}

// ---------------- launch ----------------

extern "C" void kernel_launch(void* const* d_in, const int* in_sizes, int n_in,
                              void* d_out, int out_size, void* d_ws, size_t ws_size,
                              hipStream_t stream)
{
  const float* scalar_state = (const float*)d_in[0];
  const float* vector_state = (const float*)d_in[1];
  const float* edge_attr    = (const float*)d_in[2];
  const float* edge_vector  = (const float*)d_in[3];
  const float* sn_g = (const float*)d_in[4];
  const float* sn_b = (const float*)d_in[5];
  const float* pn_g = (const float*)d_in[6];
  const float* pn_b = (const float*)d_in[7];
  const float* e_w1 = (const float*)d_in[8];
  const float* e_b1 = (const float*)d_in[9];
  const float* e_w2 = (const float*)d_in[10];
  const float* e_b2 = (const float*)d_in[11];
  const float* n_w1 = (const float*)d_in[12];
  const float* n_b1 = (const float*)d_in[13];
  const float* n_w2 = (const float*)d_in[14];
  const float* n_b2 = (const float*)d_in[15];
  const int*   eidx = (const int*)d_in[16];

  char* p = (char*)d_ws;
  auto take = [&](size_t bytes)->char*{
    char* r = p; p += (bytes + 255) & ~(size_t)255; return r;
  };
  int*      flag    = (int*)take(4);
  ushort_t* s_norm  = (ushort_t*)take((size_t)N_NODES*128*2);
  ushort_t* Wabp    = (ushort_t*)take((size_t)128*640*2);
  ushort_t* W1cp    = (ushort_t*)take((size_t)64*320*2);
  ushort_t* W2p     = (ushort_t*)take((size_t)320*320*2);
  ushort_t* W1np    = (ushort_t*)take((size_t)160*288*2);
  ushort_t* W2np    = (ushort_t*)take((size_t)288*160*2);
  int*      counts  = (int*)take((size_t)N_NODES*4);
  int*      offsets = (int*)take((size_t)N_NODES*4);
  int*      cursor  = (int*)take((size_t)N_NODES*4);
  int*      sorted  = (int*)take((size_t)N_EDGES*4);
  ushort_t* Pbuf    = (ushort_t*)take((size_t)N_NODES*640*2);
  ushort_t* msg     = (ushort_t*)take((size_t)N_EDGES*192*2);
  ushort_t* node_in = (ushort_t*)take((size_t)N_NODES*160*2);
  (void)ws_size; (void)in_sizes; (void)n_in; (void)out_size;

  float* outS = (float*)d_out;
  float* outV = outS + (size_t)N_NODES*128;

  kDetect<<<1, 64, 0, stream>>>(eidx, flag);
  kLN<<<(N_NODES+3)/4, 256, 0, stream>>>(scalar_state, sn_g, sn_b, s_norm, N_NODES);
  kReorderAB<<<160, 256, 0, stream>>>(e_w1, Wabp);
  kReorder<<<160, 256, 0, stream>>>(e_w1 + (size_t)256*320, W1cp, 64, 320);
  kReorder<<<160, 256, 0, stream>>>(e_w2, W2p, 320, 320);
  kReorder<<<160, 256, 0, stream>>>(n_w1, W1np, 160, 288);
  kReorder<<<160, 256, 0, stream>>>(n_w2, W2np, 288, 160);
  hipMemsetAsync(counts, 0, (size_t)N_NODES*4, stream);
  kHist<<<N_EDGES/256, 256, 0, stream>>>(eidx, flag, counts);
  kScan<<<1, 1024, 0, stream>>>(counts, offsets, cursor, N_NODES);
  kScatter<<<N_EDGES/256, 256, 0, stream>>>(eidx, flag, cursor, sorted);
  kNodeP<<<(N_NODES+63)/64, 256, 0, stream>>>(s_norm, Wabp, e_b1, Pbuf);
  kEdgeMLP<<<N_EDGES/64, 256, 0, stream>>>(Pbuf, edge_attr, W1cp, W2p,
                                           e_b2, eidx, flag, msg);
  kAgg<<<N_NODES, 128, 0, stream>>>(msg, sorted, counts, offsets,
                                    scalar_state, vector_state, edge_vector,
                                    eidx, flag, pn_g, pn_b, outS, outV, node_in);
  kNodeMLP<<<(N_NODES+31)/32, 256, 0, stream>>>(node_in, W1np, W2np, n_b1, n_b2, outS, outV);
}

// Round 3
// 1232.742 us; speedup vs baseline: 1.6592x; 1.2787x over previous
//
#include <hip/hip_runtime.h>

#define N_NODES 50000
#define N_EDGES 800000

typedef __attribute__((ext_vector_type(8))) short short8;
typedef __attribute__((ext_vector_type(4))) float floatx4;
typedef __attribute__((ext_vector_type(4))) unsigned int u32x4;
typedef unsigned short ushort_t;
typedef unsigned int uint_t;

__device__ __forceinline__ ushort_t f2bf(float f){
  unsigned u = __builtin_bit_cast(unsigned, f);
  u += 0x7fffu + ((u >> 16) & 1u);           // round-to-nearest-even
  return (ushort_t)(u >> 16);
}
__device__ __forceinline__ float bf2f(ushort_t h){
  unsigned u = ((unsigned)h) << 16;
  return __builtin_bit_cast(float, u);
}
// packed f32x2 -> bf16x2 (HW v_cvt_pk_bf16_f32 on gfx950 if available)
__device__ __forceinline__ uint_t pkbf(float lo, float hi){
#if __has_builtin(__builtin_amdgcn_cvt_pk_bf16_f32)
  typedef __attribute__((ext_vector_type(2))) __bf16 bf16x2;
  bf16x2 r = __builtin_amdgcn_cvt_pk_bf16_f32(lo, hi);
  return __builtin_bit_cast(uint_t, r);
#else
  return (uint_t)f2bf(lo) | ((uint_t)f2bf(hi) << 16);
#endif
}
__device__ __forceinline__ float sigm(float x){ return 1.f/(1.f+__expf(-x)); }
__device__ __forceinline__ float waveRed(float v){
  #pragma unroll
  for (int o=32;o>0;o>>=1) v += __shfl_xor(v,o);
  return v;
}
__device__ __forceinline__ int ldIdx(const int* __restrict__ idx, long long pos, int mode){
  return mode ? idx[pos*2] : idx[pos];
}
__device__ __forceinline__ short8 as_s8(u32x4 v){ return __builtin_bit_cast(short8, v); }

// async global->LDS 16B: lds dest = wave-uniform base + lane*16
__device__ __forceinline__ void gl_lds16(const ushort_t* g, ushort_t* l){
  __builtin_amdgcn_global_load_lds(
    (const __attribute__((address_space(1))) unsigned int*)(unsigned long long)(uintptr_t)g,
    (__attribute__((address_space(3))) unsigned int*)(unsigned int)(uintptr_t)l,
    16, 0, 0);
}

__device__ __forceinline__ u32x4 bfadd8(u32x4 a, u32x4 b){
  u32x4 r;
  #pragma unroll
  for (int i=0;i<4;++i){
    float alo = __builtin_bit_cast(float, a[i]<<16);
    float ahi = __builtin_bit_cast(float, a[i]&0xffff0000u);
    float blo = __builtin_bit_cast(float, b[i]<<16);
    float bhi = __builtin_bit_cast(float, b[i]&0xffff0000u);
    r[i] = pkbf(alo+blo, ahi+bhi);
  }
  return r;
}
__device__ __forceinline__ short8 pack8(floatx4 x, floatx4 y){
  u32x4 u;
  u[0] = pkbf(x[0], x[1]); u[1] = pkbf(x[2], x[3]);
  u[2] = pkbf(y[0], y[1]); u[3] = pkbf(y[2], y[3]);
  return __builtin_bit_cast(short8, u);
}

// ---------------- prep kernels ----------------

__global__ void kDetect(const int* __restrict__ idx, int* __restrict__ flag){
  if (threadIdx.x==0 && blockIdx.x==0){
    int any = 0;
    for (int i=1;i<64;i+=2) any |= idx[i];   // all-zero odd dwords => int64
    *flag = (any==0) ? 1 : 0;
  }
}

__global__ void kLN(const float* __restrict__ s, const float* __restrict__ g,
                    const float* __restrict__ b, ushort_t* __restrict__ out, int N){
  int wid = threadIdx.x >> 6, lane = threadIdx.x & 63;
  int n = blockIdx.x*4 + wid;
  if (n >= N) return;
  float x0 = s[(size_t)n*128 + lane], x1 = s[(size_t)n*128 + 64 + lane];
  float sum = waveRed(x0 + x1);
  float sq  = waveRed(x0*x0 + x1*x1);
  float mean = sum * (1.f/128.f);
  float var  = sq * (1.f/128.f) - mean*mean;
  float rstd = rsqrtf(var + 1e-5f);
  out[(size_t)n*128 + lane]      = f2bf((x0-mean)*rstd*g[lane] + b[lane]);
  out[(size_t)n*128 + 64 + lane] = f2bf((x1-mean)*rstd*g[64+lane] + b[64+lane]);
}

// W[K][OUT] f32 -> bf16 Wp[kt][q][n][j] (k = kt*32+q*8+j): B-frag = contiguous 16B
__global__ void kReorder(const float* __restrict__ W, ushort_t* __restrict__ Wp,
                         int K, int OUT){
  int total = K*OUT;
  for (int o = blockIdx.x*blockDim.x + threadIdx.x; o < total; o += gridDim.x*blockDim.x){
    int j = o & 7; int rest = o >> 3;
    int nn = rest % OUT; int qk = rest / OUT;
    int q = qk & 3, kt = qk >> 2;
    int k = kt*32 + q*8 + j;
    Wp[o] = f2bf(W[(size_t)k*OUT + nn]);
  }
}

// Wab[k<128][n<640]: n<320 -> e_w1[k][n] (tgt), n>=320 -> e_w1[128+k][n-320] (src)
__global__ void kReorderAB(const float* __restrict__ W, ushort_t* __restrict__ Wp){
  int total = 128*640;
  for (int o = blockIdx.x*blockDim.x + threadIdx.x; o < total; o += gridDim.x*blockDim.x){
    int j = o & 7; int rest = o >> 3;
    int nn = rest % 640; int qk = rest / 640;
    int q = qk & 3, kt = qk >> 2;
    int k = kt*32 + q*8 + j;
    float v = (nn < 320) ? W[(size_t)k*320 + nn] : W[(size_t)(128+k)*320 + (nn-320)];
    Wp[o] = f2bf(v);
  }
}

// ---------------- counting sort of edges by tgt ----------------

__global__ void kHist(const int* __restrict__ idx, const int* __restrict__ flagp,
                      int* __restrict__ counts){
  int mode = *flagp;
  long long e = (long long)blockIdx.x*256 + threadIdx.x;
  if (e < N_EDGES) atomicAdd(&counts[ldIdx(idx, e, mode)], 1);
}

// 3-kernel scan: per-block shuffle scan, block-sums scan, add-back.
__global__ void kScanLocal(const int* __restrict__ counts, int* __restrict__ offsets,
                           int* __restrict__ bsum, int n){
  int tid = threadIdx.x, lane = tid & 63, wid = tid >> 6;
  int i = blockIdx.x*1024 + tid;
  int x = (i<n) ? counts[i] : 0;
  int v = x;
  #pragma unroll
  for (int o=1;o<64;o<<=1){ int t = __shfl_up(v,o); if (lane>=o) v += t; }
  __shared__ int ws[16];
  if (lane==63) ws[wid] = v;
  __syncthreads();
  if (wid==0){
    int s = (lane<16) ? ws[lane] : 0;
    #pragma unroll
    for (int o=1;o<16;o<<=1){ int t = __shfl_up(s,o); if (lane>=o) s += t; }
    if (lane<16) ws[lane] = s;
  }
  __syncthreads();
  int base = wid ? ws[wid-1] : 0;
  if (i<n) offsets[i] = base + v - x;           // block-local exclusive
  if (tid==1023) bsum[blockIdx.x] = ws[15];
}
__global__ void kScanSums(const int* __restrict__ bsum, int* __restrict__ bbase, int nb){
  int lane = threadIdx.x;
  int x = (lane<nb) ? bsum[lane] : 0;
  int v = x;
  #pragma unroll
  for (int o=1;o<64;o<<=1){ int t = __shfl_up(v,o); if (lane>=o) v += t; }
  if (lane<nb) bbase[lane] = v - x;
}
__global__ void kScanAdd(int* __restrict__ offsets, int* __restrict__ cursor,
                         const int* __restrict__ bbase, int n){
  int i = blockIdx.x*1024 + threadIdx.x;
  if (i<n){ int v = offsets[i] + bbase[blockIdx.x]; offsets[i]=v; cursor[i]=v; }
}

// scatter: sorted pos -> edge id, tgt (u16), aux {src, unit xyz} (16B)
__global__ void kScatter(const int* __restrict__ idx, const int* __restrict__ flagp,
                         int* __restrict__ cursor, const float* __restrict__ edge_vector,
                         int* __restrict__ sortedE, ushort_t* __restrict__ sortedT,
                         floatx4* __restrict__ aux){
  int mode = *flagp;
  long long e = (long long)blockIdx.x*256 + threadIdx.x;
  if (e < N_EDGES){
    int t = ldIdx(idx, e, mode);
    int s = ldIdx(idx, (long long)N_EDGES + e, mode);
    float ex = edge_vector[e*3], ey = edge_vector[e*3+1], ez = edge_vector[e*3+2];
    float inr = 1.f / fmaxf(sqrtf(ex*ex+ey*ey+ez*ez), 1e-8f);
    int pos = atomicAdd(&cursor[t], 1);
    sortedE[pos] = (int)e;
    sortedT[pos] = (ushort_t)t;
    floatx4 a; a[0] = __int_as_float(s); a[1] = ex*inr; a[2] = ey*inr; a[3] = ez*inr;
    aux[pos] = a;
  }
}

// ---------------- node-level P: P[n][0:320]=s_norm@W1a+b1, [320:640]=s_norm@W1b ----
__global__ __launch_bounds__(256,2) void kNodeP(
  const ushort_t* __restrict__ s_norm, const ushort_t* __restrict__ Wabp,
  const float* __restrict__ b1, ushort_t* __restrict__ P)
{
  __shared__ u32x4 sA[1024];   // 16KB
  __shared__ u32x4 sB[2560];   // 40KB
  const int tid = threadIdx.x;
  const int lane = tid & 63, wid = tid >> 6;
  const int col = lane & 15, quad = lane >> 4;
  const int nb0 = blockIdx.x * 64;

  for (int i=0;i<4;++i){
    int d = i*256 + tid;
    int m=d&15, q=(d>>4)&3, mt=(d>>6)&3, kt=d>>8;
    int node = nb0 + mt*16 + m;
    u32x4 v = {0,0,0,0};
    if (node < N_NODES) v = *(const u32x4*)(s_norm + (size_t)node*128 + (kt*4+q)*8);
    sA[d] = v;
  }

  const floatx4 zz = {0.f,0.f,0.f,0.f};
  floatx4 acc[10][4];
  #pragma unroll
  for (int i=0;i<10;++i)
    #pragma unroll
    for (int j=0;j<4;++j) acc[i][j] = zz;

  for (int kt=0; kt<4; ++kt){
    for (int i=0;i<10;++i){
      int cb = i*256 + wid*64;
      gl_lds16(Wabp + ((size_t)kt*2560 + cb + lane)*8, (ushort_t*)&sB[cb]);
    }
    __syncthreads();
    short8 a[4];
    #pragma unroll
    for (int mt=0; mt<4; ++mt)
      a[mt] = as_s8(sA[((kt*4+mt)*4+quad)*16 + col]);
    #pragma unroll
    for (int nt=0; nt<10; ++nt){
      int n = wid*160 + nt*16 + col;
      short8 b = as_s8(sB[quad*640 + n]);
      #pragma unroll
      for (int mt=0; mt<4; ++mt)
        acc[nt][mt] = __builtin_amdgcn_mfma_f32_16x16x32_bf16(a[mt], b, acc[nt][mt], 0,0,0);
    }
    __syncthreads();
  }

  #pragma unroll
  for (int nt=0; nt<10; ++nt){
    int n = wid*160 + nt*16 + col;
    float bias = (n < 320) ? b1[n] : 0.f;
    #pragma unroll
    for (int mt=0; mt<4; ++mt)
      #pragma unroll
      for (int reg=0; reg<4; ++reg){
        int node = nb0 + mt*16 + quad*4 + reg;
        if (node < N_NODES)
          P[(size_t)node*640 + n] = f2bf(acc[nt][mt][reg] + bias);
      }
  }
}

// ---------------- fused edge MLP v3: sorted order, direct-global B ----------------
__global__ __launch_bounds__(256,3) void kEdgeMLP(
    const ushort_t* __restrict__ P, const float* __restrict__ edge_attr,
    const ushort_t* __restrict__ W1cp, const ushort_t* __restrict__ W2p,
    const float* __restrict__ b2, const int* __restrict__ sortedE,
    const ushort_t* __restrict__ sortedT, const floatx4* __restrict__ aux,
    ushort_t* __restrict__ msg)
{
  __shared__ u32x4 sA[2560];          // 40KB: P-sum -> h (frag order) -> plain upd
  __shared__ int sTgt[64], sSrc[64], sE[64];
  const int tid = threadIdx.x;
  const int lane = tid & 63, wid = tid >> 6;
  const int col = lane & 15, quad = lane >> 4;
  const long long p0 = (long long)blockIdx.x * 64;
  const int nb = wid * 80;

  if (tid < 64){
    sTgt[tid] = (int)sortedT[p0 + tid];
    sE[tid]   = sortedE[p0 + tid];
    sSrc[tid] = __float_as_int(aux[p0 + tid][0]);
  }
  __syncthreads();

  // edge_attr A-fragments (gathered rows, 256B-aligned) -> registers
  short8 aQ[2][4];
  #pragma unroll
  for (int kq=0; kq<2; ++kq)
    #pragma unroll
    for (int mt=0; mt<4; ++mt){
      const float* fp = edge_attr + (size_t)sE[mt*16+col]*64 + kq*32 + quad*8;
      aQ[kq][mt] = pack8(*(const floatx4*)fp, *(const floatx4*)(fp+4));
    }

  // stage sP = P[tgt][n] + P[src][320+n] into sA (A-frag order over k=n)
  for (int i=0;i<10;++i){
    int d = i*256 + tid;
    int m=d&15, q=(d>>4)&3, mt=(d>>6)&3, kt=d>>8;
    int r = mt*16 + m;
    int n0 = kt*32 + q*8;
    u32x4 a = *(const u32x4*)(P + (size_t)sTgt[r]*640 + n0);
    u32x4 b = *(const u32x4*)(P + (size_t)sSrc[r]*640 + 320 + n0);
    sA[d] = bfadd8(a, b);
  }
  __syncthreads();

  const floatx4 zz = {0.f,0.f,0.f,0.f};
  floatx4 acc[5][4];
  #pragma unroll
  for (int i=0;i<5;++i)
    #pragma unroll
    for (int j=0;j<4;++j) acc[i][j] = zz;

  // Q GEMM: edge_attr @ W1c (K=64), B direct from global (L2-resident)
  #pragma unroll
  for (int kq=0; kq<2; ++kq)
    #pragma unroll
    for (int nt=0; nt<5; ++nt){
      short8 b = as_s8(*(const u32x4*)(W1cp + ((size_t)(kq*4+quad)*320 + nb + nt*16 + col)*8));
      #pragma unroll
      for (int mt=0; mt<4; ++mt)
        acc[nt][mt] = __builtin_amdgcn_mfma_f32_16x16x32_bf16(aQ[kq][mt], b, acc[nt][mt], 0,0,0);
    }

  // epi1: h = silu(acc + sP) in place (per-element owner bijection)
  ushort_t* sH16 = (ushort_t*)sA;
  #pragma unroll
  for (int nt=0; nt<5; ++nt){
    int n = nb + nt*16 + col;
    int kt_h = n>>5, q_h = (n>>3)&3, j_h = n&7;
    #pragma unroll
    for (int mt=0; mt<4; ++mt)
      #pragma unroll
      for (int reg=0; reg<4; ++reg){
        int ml = quad*4 + reg;
        int a2 = (((kt_h*4 + mt)*4 + q_h)*16 + ml)*8 + j_h;
        float x = acc[nt][mt][reg] + bf2f(sH16[a2]);
        sH16[a2] = f2bf(x * sigm(x));
      }
  }
  #pragma unroll
  for (int i=0;i<5;++i)
    #pragma unroll
    for (int j=0;j<4;++j) acc[i][j] = zz;
  __syncthreads();

  // GEMM2: K=320 in 10 K=32 rounds, B direct from global, NO barriers in loop
  const ushort_t* wb = W2p + ((size_t)quad*320 + nb + col)*8;
  for (int kt=0; kt<10; ++kt){
    short8 bfr[5];
    #pragma unroll
    for (int nt=0; nt<5; ++nt)
      bfr[nt] = as_s8(*(const u32x4*)(wb + (size_t)kt*10240 + nt*128));
    short8 a[4];
    #pragma unroll
    for (int mt=0; mt<4; ++mt)
      a[mt] = as_s8(sA[((kt*4+mt)*4+quad)*16 + col]);
    #pragma unroll
    for (int nt=0; nt<5; ++nt)
      #pragma unroll
      for (int mt=0; mt<4; ++mt)
        acc[nt][mt] = __builtin_amdgcn_mfma_f32_16x16x32_bf16(a[mt], bfr[nt], acc[nt][mt], 0,0,0);
  }
  __syncthreads();   // all A-frag reads done before epi2 overwrites sA

  // epi2: upd + b2 -> plain [64][320] bf16 in sA
  #pragma unroll
  for (int nt=0; nt<5; ++nt){
    int n = nb + nt*16 + col;
    float bias = b2[n];
    #pragma unroll
    for (int mt=0; mt<4; ++mt)
      #pragma unroll
      for (int reg=0; reg<4; ++reg){
        int mrow = mt*16 + quad*4 + reg;
        sH16[mrow*320 + n] = f2bf(acc[nt][mt][reg] + bias);
      }
  }
  __syncthreads();

  // gating -> msg rows (at sorted pos) of 192 bf16 (96 packed uints)
  for (int pck = tid; pck < 6144; pck += 256){
    int r = pck / 96, u = pck % 96;
    float v0, v1;
    if (u < 64){
      int c0 = u*2;
      float a0 = bf2f(sH16[r*320 + c0]),   g0 = bf2f(sH16[r*320 + 128 + c0]);
      float a1 = bf2f(sH16[r*320 + c0+1]), g1 = bf2f(sH16[r*320 + 128 + c0+1]);
      v0 = a0 * sigm(g0); v1 = a1 * sigm(g1);
    } else if (u < 80){
      int vv = (u-64)*2;
      v0 = sigm(bf2f(sH16[r*320 + 256 + vv]));
      v1 = sigm(bf2f(sH16[r*320 + 256 + vv+1]));
    } else {
      int vv = (u-80)*2;
      v0 = bf2f(sH16[r*320 + 288 + vv]);
      v1 = bf2f(sH16[r*320 + 288 + vv+1]);
    }
    ((uint_t*)msg)[(size_t)(p0 + r)*96 + u] = pkbf(v0, v1);
  }
}

// ---------------- per-node aggregation (contiguous msg rows) ----------------
__global__ __launch_bounds__(128) void kAgg(
  const ushort_t* __restrict__ msg, const floatx4* __restrict__ aux,
  const int* __restrict__ counts, const int* __restrict__ offsets,
  const float* __restrict__ scalar_state, const float* __restrict__ vector_state,
  const float* __restrict__ pn_g, const float* __restrict__ pn_b,
  float* __restrict__ outS, float* __restrict__ outV, ushort_t* __restrict__ node_in)
{
  int n = blockIdx.x, t = threadIdx.x;
  int cnt = counts[n], start = offsets[n];
  int c = t >> 5, vv = t & 31;
  float accS = 0.f, accV = 0.f;
  for (int i=0; i<cnt; ++i){
    const ushort_t* row = msg + (size_t)(start+i)*192;
    accS += bf2f(row[t]);
    if (t < 96){
      floatx4 a = aux[start+i];
      int src = __float_as_int(a[0]);
      float sg  = bf2f(row[128+vv]);
      float dsv = bf2f(row[160+vv]);
      float sv = vector_state[(size_t)src*96 + t];
      float uc = (c==0) ? a[1] : (c==1) ? a[2] : a[3];
      accV += sv*sg + uc*dsv;
    }
  }
  float inv = 1.f / fmaxf((float)cnt, 1.f);
  __shared__ float lv[96];
  __shared__ float pS[2], pQ[2];
  float s1 = scalar_state[(size_t)n*128 + t] + accS*inv;
  outS[(size_t)n*128 + t] = s1;
  if (t < 96){
    float v1 = vector_state[(size_t)n*96 + t] + accV*inv;
    outV[(size_t)n*96 + t] = v1;
    lv[t] = v1;
  }
  float wsum = waveRed(s1), wsq = waveRed(s1*s1);
  if ((t&63)==0){ pS[t>>6]=wsum; pQ[t>>6]=wsq; }
  __syncthreads();
  float mean = (pS[0]+pS[1]) * (1.f/128.f);
  float var  = (pQ[0]+pQ[1]) * (1.f/128.f) - mean*mean;
  float rstd = rsqrtf(var + 1e-5f);
  node_in[(size_t)n*160 + t] = f2bf((s1-mean)*rstd*pn_g[t] + pn_b[t]);
  if (t < 32){
    float a = lv[t], b = lv[32+t], d = lv[64+t];
    float vn = sqrtf(fmaxf(a*a+b*b+d*d, 1e-8f));
    node_in[(size_t)n*160 + 128 + t] = f2bf(vn);
  }
}

// ---------------- fused node MLP (direct-global B, 2 barriers) ----------------
__global__ __launch_bounds__(256,2) void kNodeMLP(
  const ushort_t* __restrict__ node_in, const ushort_t* __restrict__ W1np,
  const ushort_t* __restrict__ W2np, const float* __restrict__ b1,
  const float* __restrict__ b2, float* __restrict__ outS, float* __restrict__ outV)
{
  __shared__ u32x4 sA[640];    // 10KB
  __shared__ u32x4 sH[1152];   // 18KB
  const int tid = threadIdx.x;
  const int lane = tid & 63, wid = tid >> 6;
  const int col = lane & 15, quad = lane >> 4;
  const int wm = wid & 1, wn = wid >> 1;
  const int rbase = blockIdx.x * 32;

  for (int d = tid; d < 640; d += 256){
    int m = d & 15, q = (d>>4)&3, mtile = (d>>6)&1, kt = d>>7;
    int r = rbase + mtile*16 + m, cc = kt*4 + q;
    u32x4 v = {0,0,0,0};
    if (r < N_NODES) v = *(const u32x4*)(node_in + (size_t)r*160 + cc*8);
    sA[d] = v;
  }
  __syncthreads();

  const floatx4 zz = {0.f,0.f,0.f,0.f};
  floatx4 acc[9];
  #pragma unroll
  for (int i=0;i<9;++i) acc[i] = zz;

  for (int kt=0; kt<5; ++kt){
    short8 a = as_s8(sA[((kt*2+wm)*4+quad)*16 + col]);
    #pragma unroll
    for (int jt=0; jt<9; ++jt){
      int n = wn*144 + jt*16 + col;
      short8 b = as_s8(*(const u32x4*)(W1np + (size_t)kt*9216 + ((size_t)quad*288 + n)*8));
      acc[jt] = __builtin_amdgcn_mfma_f32_16x16x32_bf16(a, b, acc[jt], 0,0,0);
    }
  }
  ushort_t* sH16 = (ushort_t*)sH;
  #pragma unroll
  for (int jt=0; jt<9; ++jt){
    int n = wn*144 + jt*16 + col;
    float bias = b1[n];
    int kt_h = n>>5, q_h = (n>>3)&3, j_h = n&7;
    #pragma unroll
    for (int reg=0; reg<4; ++reg){
      int ml = quad*4 + reg;
      float x = acc[jt][reg] + bias;
      float s = x * sigm(x);
      int chunk = ((kt_h*2 + wm)*4 + q_h)*16 + ml;
      sH16[chunk*8 + j_h] = f2bf(s);
    }
  }
  __syncthreads();

  floatx4 acc2[5];
  #pragma unroll
  for (int i=0;i<5;++i) acc2[i] = zz;

  for (int kt=0; kt<9; ++kt){
    short8 a = as_s8(sH[((kt*2+wm)*4+quad)*16 + col]);
    #pragma unroll
    for (int jt=0; jt<5; ++jt){
      int n = wn*80 + jt*16 + col;
      short8 b = as_s8(*(const u32x4*)(W2np + (size_t)kt*5120 + ((size_t)quad*160 + n)*8));
      acc2[jt] = __builtin_amdgcn_mfma_f32_16x16x32_bf16(a, b, acc2[jt], 0,0,0);
    }
  }

  #pragma unroll
  for (int jt=0; jt<5; ++jt){
    int n = wn*80 + jt*16 + col;
    float bias = b2[n];
    #pragma unroll
    for (int reg=0; reg<4; ++reg){
      int ml = quad*4 + reg;
      int r = rbase + wm*16 + ml;
      if (r < N_NODES){
        float val = acc2[jt][reg] + bias;
        if (n < 128){
          float* o = outS + (size_t)r*128 + n;
          *o = *o + val;
        } else {
          int vv = n - 128;
          float f = 1.f + 0.1f * tanhf(val);
          float* o = outV + (size_t)r*96 + vv;
          o[0] *= f; o[32] *= f; o[64] *= f;
        }
      }
    }
  }
}

// ---------------- launch ----------------

extern "C" void kernel_launch(void* const* d_in, const int* in_sizes, int n_in,
                              void* d_out, int out_size, void* d_ws, size_t ws_size,
                              hipStream_t stream)
{
  const float* scalar_state = (const float*)d_in[0];
  const float* vector_state = (const float*)d_in[1];
  const float* edge_attr    = (const float*)d_in[2];
  const float* edge_vector  = (const float*)d_in[3];
  const float* sn_g = (const float*)d_in[4];
  const float* sn_b = (const float*)d_in[5];
  const float* pn_g = (const float*)d_in[6];
  const float* pn_b = (const float*)d_in[7];
  const float* e_w1 = (const float*)d_in[8];
  const float* e_b1 = (const float*)d_in[9];
  const float* e_w2 = (const float*)d_in[10];
  const float* e_b2 = (const float*)d_in[11];
  const float* n_w1 = (const float*)d_in[12];
  const float* n_b1 = (const float*)d_in[13];
  const float* n_w2 = (const float*)d_in[14];
  const float* n_b2 = (const float*)d_in[15];
  const int*   eidx = (const int*)d_in[16];

  char* p = (char*)d_ws;
  auto take = [&](size_t bytes)->char*{
    char* r = p; p += (bytes + 255) & ~(size_t)255; return r;
  };
  int*      flag    = (int*)take(4);
  ushort_t* s_norm  = (ushort_t*)take((size_t)N_NODES*128*2);
  ushort_t* Wabp    = (ushort_t*)take((size_t)128*640*2);
  ushort_t* W1cp    = (ushort_t*)take((size_t)64*320*2);
  ushort_t* W2p     = (ushort_t*)take((size_t)320*320*2);
  ushort_t* W1np    = (ushort_t*)take((size_t)160*288*2);
  ushort_t* W2np    = (ushort_t*)take((size_t)288*160*2);
  int*      counts  = (int*)take((size_t)N_NODES*4);
  int*      offsets = (int*)take((size_t)N_NODES*4);
  int*      cursor  = (int*)take((size_t)N_NODES*4);
  int*      bsum    = (int*)take(64*4);
  int*      bbase   = (int*)take(64*4);
  int*      sortedE = (int*)take((size_t)N_EDGES*4);
  ushort_t* sortedT = (ushort_t*)take((size_t)N_EDGES*2);
  floatx4*  aux     = (floatx4*)take((size_t)N_EDGES*16);
  ushort_t* Pbuf    = (ushort_t*)take((size_t)N_NODES*640*2);
  ushort_t* msg     = (ushort_t*)take((size_t)N_EDGES*192*2);
  ushort_t* node_in = Pbuf;   // alias: Pbuf dead after kEdgeMLP, node_in born in kAgg
  (void)ws_size; (void)in_sizes; (void)n_in; (void)out_size;

  float* outS = (float*)d_out;
  float* outV = outS + (size_t)N_NODES*128;

  kDetect<<<1, 64, 0, stream>>>(eidx, flag);
  kLN<<<(N_NODES+3)/4, 256, 0, stream>>>(scalar_state, sn_g, sn_b, s_norm, N_NODES);
  kReorderAB<<<160, 256, 0, stream>>>(e_w1, Wabp);
  kReorder<<<160, 256, 0, stream>>>(e_w1 + (size_t)256*320, W1cp, 64, 320);
  kReorder<<<160, 256, 0, stream>>>(e_w2, W2p, 320, 320);
  kReorder<<<160, 256, 0, stream>>>(n_w1, W1np, 160, 288);
  kReorder<<<160, 256, 0, stream>>>(n_w2, W2np, 288, 160);
  hipMemsetAsync(counts, 0, (size_t)N_NODES*4, stream);
  kHist<<<N_EDGES/256, 256, 0, stream>>>(eidx, flag, counts);
  int nsb = (N_NODES + 1023)/1024;   // 49
  kScanLocal<<<nsb, 1024, 0, stream>>>(counts, offsets, bsum, N_NODES);
  kScanSums<<<1, 64, 0, stream>>>(bsum, bbase, nsb);
  kScanAdd<<<nsb, 1024, 0, stream>>>(offsets, cursor, bbase, N_NODES);
  kScatter<<<N_EDGES/256, 256, 0, stream>>>(eidx, flag, cursor, edge_vector,
                                            sortedE, sortedT, aux);
  kNodeP<<<(N_NODES+63)/64, 256, 0, stream>>>(s_norm, Wabp, e_b1, Pbuf);
  kEdgeMLP<<<N_EDGES/64, 256, 0, stream>>>(Pbuf, edge_attr, W1cp, W2p,
                                           e_b2, sortedE, sortedT, aux, msg);
  kAgg<<<N_NODES, 128, 0, stream>>>(msg, aux, counts, offsets,
                                    scalar_state, vector_state,
                                    pn_g, pn_b, outS, outV, node_in);
  kNodeMLP<<<(N_NODES+31)/32, 256, 0, stream>>>(node_in, W1np, W2np, n_b1, n_b2, outS, outV);
}